// Round 3
// baseline (15123.749 us; speedup 1.0000x reference)
//
#include <hip/hip_runtime.h>
#include <cstdio>

#define NODES 153600
#define PJ 150
#define NJETS 1024
#define DEG 16
#define NEDGE (NODES*DEG)
#define HD 256
#define NCL 10

typedef unsigned short u16;  // fp16 storage (bit pattern)

__device__ inline float h2f(u16 u) { union { u16 s; _Float16 h; } v; v.s = u; return (float)v.h; }
__device__ inline u16 f2h(float f) { union { u16 s; _Float16 h; } v; v.h = (_Float16)f; return v.s; }

template<typename T> __device__ inline float ldv(const T* p);
template<> __device__ inline float ldv<float>(const float* p) { return *p; }
template<> __device__ inline float ldv<u16>(const u16* p) { return h2f(*p); }
template<typename T> __device__ inline void stv(T* p, float v);
template<> __device__ inline void stv<float>(float* p, float v) { *p = v; }
template<> __device__ inline void stv<u16>(u16* p, float v) { *p = f2h(v); }

// ---------------- diagnostic ----------------
__global__ void k_diag(float* out, float code) {
  if (blockIdx.x == 0 && threadIdx.x == 0) out[0] = code;
}

// ---------------- graph preprocessing ----------------

__global__ __launch_bounds__(256) void k_dis(const int* __restrict__ tgt, float* __restrict__ dis) {
  int n = blockIdx.x*256 + threadIdx.x;
  if (n >= NODES) return;
  int cnt = 0;
#pragma unroll
  for (int j = 0; j < DEG; ++j) cnt += (tgt[n*DEG + j] != n) ? 1 : 0;
  dis[n] = (cnt > 0) ? rsqrtf((float)cnt) : 0.f;
}

__global__ __launch_bounds__(256) void k_counts(const int* __restrict__ tgt, int* __restrict__ counts) {
  int e = blockIdx.x*256 + threadIdx.x;
  if (e >= NEDGE) return;
  atomicAdd(&counts[tgt[e]], 1);
}

__global__ __launch_bounds__(256) void k_scan(const int* __restrict__ counts, int* __restrict__ rowptr, int* __restrict__ cursor) {
  int j = blockIdx.x*256 + threadIdx.x;
  if (j >= NJETS) return;
  int run = j*PJ*DEG;  // jet j's target edges occupy exactly [2400j, 2400(j+1))
  for (int l = 0; l < PJ; ++l) {
    int idx = j*PJ + l;
    int cnt = counts[idx];
    rowptr[idx] = run;
    cursor[idx] = run;
    run += cnt;
  }
  if (j == 0) rowptr[NODES] = NEDGE;
}

__global__ __launch_bounds__(256) void k_fill(const int* __restrict__ src_, const int* __restrict__ tgt_,
                                              const float* __restrict__ dis, int* __restrict__ cursor,
                                              unsigned char* __restrict__ ccol, float* __restrict__ cw) {
  int e = blockIdx.x*256 + threadIdx.x;
  if (e >= NEDGE) return;
  int s = src_[e], t = tgt_[e];
  int pos = atomicAdd(&cursor[t], 1);
  ccol[pos] = (unsigned char)(s % PJ);               // jet-local src index (<150)
  cw[pos] = (s != t) ? -(dis[s]*dis[t]) : 0.f;       // scaled-Laplacian weight
}

// ---------------- layer 1 (din=3, fp32 scratch) ----------------

__global__ __launch_bounds__(256) void k_tall0(const float* __restrict__ x, float* __restrict__ tall) {
  int n = blockIdx.x*256 + threadIdx.x;
  if (n >= NODES) return;
  tall[n*18+0] = x[n*3+0]; tall[n*18+1] = x[n*3+1]; tall[n*18+2] = x[n*3+2];
}

__global__ __launch_bounds__(256) void k_prop3(const float* __restrict__ hin, const float* __restrict__ prev,
                                               float* __restrict__ out3, float* __restrict__ tallslot,
                                               float alpha, float beta,
                                               const int* __restrict__ rowptr, const unsigned char* __restrict__ ccol,
                                               const float* __restrict__ cw) {
  int t = blockIdx.x*256 + threadIdx.x;
  if (t >= NODES) return;
  int jb = (t/PJ)*PJ;
  int rs = rowptr[t], re = rowptr[t+1];
  float a0=0.f, a1=0.f, a2=0.f;
  for (int e = rs; e < re; ++e) {
    float w = cw[e];
    int s = (jb + (int)ccol[e])*3;
    a0 += w*hin[s]; a1 += w*hin[s+1]; a2 += w*hin[s+2];
  }
  float o0 = alpha*a0, o1 = alpha*a1, o2 = alpha*a2;
  if (beta != 0.f) { o0 += beta*prev[t*3]; o1 += beta*prev[t*3+1]; o2 += beta*prev[t*3+2]; }
  out3[t*3]=o0; out3[t*3+1]=o1; out3[t*3+2]=o2;
  tallslot[t*18]=o0; tallslot[t*18+1]=o1; tallslot[t*18+2]=o2;
}

// out[n,c] = sum_{i<18} Tall[n,i] * W1[i,c]   (W1 flat (6,3,256) == (18,256))
template<typename OT>
__global__ __launch_bounds__(256) void k_gemm1(const float* __restrict__ tall, const float* __restrict__ W1,
                                               OT* __restrict__ outc) {
  __shared__ float wl[18*256];
  __shared__ float tl[64*18];
  int c = threadIdx.x;
  for (int i = c; i < 18*256; i += 256) wl[i] = W1[i];
  int n0 = blockIdx.x*64;
  __syncthreads();
  for (int i = c; i < 64*18; i += 256) tl[i] = tall[(size_t)n0*18 + i];
  __syncthreads();
  for (int n = 0; n < 64; ++n) {
    float acc = 0.f;
#pragma unroll
    for (int i = 0; i < 18; ++i) acc += tl[n*18 + i] * wl[i*256 + c];
    stv(&outc[(size_t)(n0+n)*HD + c], acc);
  }
}

// ---------------- prop on 256 channels (fp16 in/out, fp32 math) ----------------
__global__ __launch_bounds__(256) void k_prop256(const u16* __restrict__ h, const u16* __restrict__ prev,
                                                 u16* __restrict__ outp, float alpha, float beta,
                                                 const int* __restrict__ rowptr, const unsigned char* __restrict__ ccol,
                                                 const float* __restrict__ cw) {
  int t = blockIdx.x;
  int c = threadIdx.x;
  int jb = (t/PJ)*PJ;
  int rs = rowptr[t], re = rowptr[t+1];
  float acc = 0.f;
  for (int e = rs; e < re; ++e) acc += cw[e] * h2f(h[(size_t)(jb+(int)ccol[e])*HD + c]);
  float o = alpha*acc;
  if (beta != 0.f) o += beta*h2f(prev[(size_t)t*HD + c]);
  outp[(size_t)t*HD + c] = f2h(o);
}

// ---------------- tiled GEMM: C[N,256] (+)= A[N,256](fp16) @ W[256,256](fp32) ----------------

template<typename OT, bool ACCUM>
__global__ __launch_bounds__(256) void k_gemm(const u16* __restrict__ A, const float* __restrict__ Wm,
                                              OT* __restrict__ C) {
  __shared__ float As[16*64];  // [k][m]
  __shared__ float Bs[16*64];  // [k][n]
  int tid = threadIdx.x;
  int tx = tid & 15, ty = tid >> 4;
  int m0 = blockIdx.x * 64, n0 = blockIdx.y * 64;
  float acc[4][4] = {};
  for (int k0 = 0; k0 < 256; k0 += 16) {
    int row = tid >> 2, kq = tid & 3;
    ushort4 av = *(const ushort4*)&A[(size_t)(m0+row)*HD + k0 + kq*4];
    As[(kq*4+0)*64 + row] = h2f(av.x);
    As[(kq*4+1)*64 + row] = h2f(av.y);
    As[(kq*4+2)*64 + row] = h2f(av.z);
    As[(kq*4+3)*64 + row] = h2f(av.w);
    float4 bv = *(const float4*)&Wm[(size_t)(k0 + (tid>>4))*256 + n0 + (tid&15)*4];
    *(float4*)&Bs[(tid>>4)*64 + (tid&15)*4] = bv;
    __syncthreads();
#pragma unroll
    for (int kk = 0; kk < 16; ++kk) {
      float4 a4 = *(const float4*)&As[kk*64 + ty*4];
      float4 b4 = *(const float4*)&Bs[kk*64 + tx*4];
      float am[4] = {a4.x, a4.y, a4.z, a4.w};
      float bn_[4] = {b4.x, b4.y, b4.z, b4.w};
#pragma unroll
      for (int i = 0; i < 4; ++i)
#pragma unroll
        for (int j = 0; j < 4; ++j) acc[i][j] += am[i]*bn_[j];
    }
    __syncthreads();
  }
#pragma unroll
  for (int i = 0; i < 4; ++i) {
    size_t r = (size_t)(m0 + ty*4 + i)*256 + n0 + tx*4;
#pragma unroll
    for (int j = 0; j < 4; ++j) {
      OT* p = &C[r + j];
      float v = acc[i][j];
      if (ACCUM) v += ldv(p);
      stv(p, v);
    }
  }
}

// ---------------- batchnorm (training stats, biased var) + leaky relu ----------------

template<typename OT>
__global__ __launch_bounds__(256) void k_bnstats(const OT* __restrict__ Cc, const float* __restrict__ bias,
                                                 float* __restrict__ stats) {
  int c = threadIdx.x;
  float bc = bias[c];
  float s = 0.f, s2 = 0.f;
  int rows_per = (NODES + gridDim.x - 1) / gridDim.x;
  int r0 = blockIdx.x * rows_per;
  int r1 = min(NODES, r0 + rows_per);
  for (int r = r0; r < r1; ++r) {
    float v = ldv(&Cc[(size_t)r*HD + c]) + bc;
    s += v; s2 += v*v;
  }
  atomicAdd(&stats[c], s);
  atomicAdd(&stats[HD + c], s2);
}

template<typename OT>
__global__ __launch_bounds__(256) void k_bnapply(const OT* __restrict__ Cc, const float* __restrict__ bias,
                                                 const float* __restrict__ stats, const float* __restrict__ g,
                                                 const float* __restrict__ be, u16* __restrict__ hout) {
  const float invN = 1.f/(float)NODES;
  int total = NODES*HD;
  for (int i = blockIdx.x*256 + threadIdx.x; i < total; i += gridDim.x*256) {
    int c = i & (HD-1);
    float m = stats[c]*invN;
    float v = stats[HD+c]*invN - m*m;
    float wq = rsqrtf(v + 1e-5f);
    float val = (ldv(&Cc[i]) + bias[c] - m)*wq*g[c] + be[c];
    hout[i] = f2h((val > 0.f) ? val : 0.01f*val);
  }
}

// ---------------- row L2 normalize (layer 4 output) ----------------

template<typename OT>
__global__ __launch_bounds__(256) void k_rownorm(const OT* __restrict__ Cc, const float* __restrict__ bias,
                                                 u16* __restrict__ hout) {
  int wave = threadIdx.x >> 6, lane = threadIdx.x & 63;
  int n = blockIdx.x*4 + wave;
  float v0 = ldv(&Cc[(size_t)n*HD + lane*4 + 0]) + bias[lane*4 + 0];
  float v1 = ldv(&Cc[(size_t)n*HD + lane*4 + 1]) + bias[lane*4 + 1];
  float v2 = ldv(&Cc[(size_t)n*HD + lane*4 + 2]) + bias[lane*4 + 2];
  float v3 = ldv(&Cc[(size_t)n*HD + lane*4 + 3]) + bias[lane*4 + 3];
  float ss = v0*v0 + v1*v1 + v2*v2 + v3*v3;
  for (int off = 32; off > 0; off >>= 1) ss += __shfl_down(ss, off, 64);
  ss = __shfl(ss, 0, 64);
  float inv = 1.f / fmaxf(sqrtf(ss), 1e-12f);
  hout[(size_t)n*HD + lane*4 + 0] = f2h(v0*inv);
  hout[(size_t)n*HD + lane*4 + 1] = f2h(v1*inv);
  hout[(size_t)n*HD + lane*4 + 2] = f2h(v2*inv);
  hout[(size_t)n*HD + lane*4 + 3] = f2h(v3*inv);
}

// ---------------- distance softmax pooling ----------------

__global__ __launch_bounds__(256) void k_pool(const u16* __restrict__ h, const float* __restrict__ x,
                                              const float* __restrict__ centers, const float* __restrict__ log_temp,
                                              float* __restrict__ out) {
  __shared__ float a_s[PJ][NCL];
  __shared__ float colsum[NCL];
  int j = blockIdx.x;
  int tid = threadIdx.x;
  float T = expf(fminf(fmaxf(log_temp[0], -2.f), 3.f));
  if (tid < PJ) {
    int g = j*PJ + tid;
    float eta = x[(size_t)g*3], phi = x[(size_t)g*3 + 1];
    float d[NCL];
    float dmin = 1e30f;
#pragma unroll
    for (int k = 0; k < NCL; ++k) {
      float dx = eta - centers[2*k], dy = phi - centers[2*k+1];
      d[k] = dx*dx + dy*dy;
      dmin = fminf(dmin, d[k]);
    }
    float s = 0.f, ek[NCL];
#pragma unroll
    for (int k = 0; k < NCL; ++k) { ek[k] = expf(-T*(d[k]-dmin)); s += ek[k]; }
    float invs = 1.f/s;
#pragma unroll
    for (int k = 0; k < NCL; ++k) a_s[tid][k] = ek[k]*invs;
  }
  __syncthreads();
  if (tid < NCL) {   // deterministic column sums
    float s = 0.f;
    for (int n = 0; n < PJ; ++n) s += a_s[n][tid];
    colsum[tid] = s;
  }
  __syncthreads();
  int c = tid;
  float acc[NCL] = {};
  for (int n = 0; n < PJ; ++n) {
    float hv = h2f(h[(size_t)(j*PJ + n)*HD + c]);
#pragma unroll
    for (int k = 0; k < NCL; ++k) acc[k] += a_s[n][k]*hv;
  }
#pragma unroll
  for (int k = 0; k < NCL; ++k)
    out[(size_t)j*(NCL*HD) + k*HD + c] = acc[k] / (colsum[k] + 1e-8f);
}

// ---------------- host ----------------

template<typename OT>
static void run_plan(const float* x, const int* srcA, const int* tgtA,
                     const float* W1, const float* b1, const float* W2, const float* b2,
                     const float* W3, const float* b3, const float* W4, const float* b4,
                     const float* g1, const float* be1, const float* g2, const float* be2,
                     const float* g3, const float* be3, const float* centers, const float* log_temp,
                     float* out, char* wp0, hipStream_t stream) {
  char* wp = wp0;
  auto alloc = [&](size_t b) -> void* {
    void* p = (void*)wp;
    wp += (b + 255) & ~(size_t)255;
    return p;
  };
  u16*   X    = (u16*)alloc((size_t)NODES*HD*2);
  u16*   Y    = (u16*)alloc((size_t)NODES*HD*2);
  OT*    OUT  = (OT*)alloc((size_t)NODES*HD*sizeof(OT));
  float* dis  = (float*)alloc((size_t)NODES*4);
  int*   counts = (int*)alloc((size_t)NODES*4);
  int*   cursor = (int*)alloc((size_t)NODES*4);
  int*   rowptr = (int*)alloc((size_t)(NODES+1)*4);
  unsigned char* ccol = (unsigned char*)alloc((size_t)NEDGE);
  float* cw     = (float*)alloc((size_t)NEDGE*4);
  float* stats  = (float*)alloc((size_t)2*HD*4);
  // layer-1 fp32 scratch aliases into Y (Y first written at layer-2 T1 prop)
  float* Tall = (float*)Y;
  float* t3a  = Tall + (size_t)NODES*18;
  float* t3b  = t3a + (size_t)NODES*3;

  // graph preprocessing
  hipMemsetAsync(counts, 0, (size_t)NODES*4, stream);
  k_dis<<<(NODES+255)/256, 256, 0, stream>>>(tgtA, dis);
  k_counts<<<(NEDGE+255)/256, 256, 0, stream>>>(tgtA, counts);
  k_scan<<<(NJETS+255)/256, 256, 0, stream>>>(counts, rowptr, cursor);
  k_fill<<<(NEDGE+255)/256, 256, 0, stream>>>(srcA, tgtA, dis, cursor, ccol, cw);

  const int NB = (NODES+255)/256;

  // ---- layer 1 (din=3) ----
  k_tall0<<<NB, 256, 0, stream>>>(x, Tall);
  k_prop3<<<NB, 256, 0, stream>>>(x,   x,   t3a, Tall+3,  1.f,  0.f, rowptr, ccol, cw);  // T1
  k_prop3<<<NB, 256, 0, stream>>>(t3a, x,   t3b, Tall+6,  2.f, -1.f, rowptr, ccol, cw);  // T2
  k_prop3<<<NB, 256, 0, stream>>>(t3b, t3a, t3a, Tall+9,  2.f, -1.f, rowptr, ccol, cw);  // T3
  k_prop3<<<NB, 256, 0, stream>>>(t3a, t3b, t3b, Tall+12, 2.f, -1.f, rowptr, ccol, cw);  // T4
  k_prop3<<<NB, 256, 0, stream>>>(t3b, t3a, t3a, Tall+15, 2.f, -1.f, rowptr, ccol, cw);  // T5
  k_gemm1<OT><<<NODES/64, 256, 0, stream>>>(Tall, W1, OUT);
  hipMemsetAsync(stats, 0, (size_t)2*HD*4, stream);
  k_bnstats<OT><<<1024, 256, 0, stream>>>(OUT, b1, stats);
  k_bnapply<OT><<<4096, 256, 0, stream>>>(OUT, b1, stats, g1, be1, X);

  // ---- layers 2..4 (din=256) ----
  const float* Ws[3]  = {W2, W3, W4};
  const float* bs[3]  = {b2, b3, b4};
  const float* gs[2]  = {g2, g3};
  const float* bes[2] = {be2, be3};
  dim3 ggrid(NODES/64, HD/64);
  for (int L = 0; L < 3; ++L) {
    const float* Wl = Ws[L];
    k_gemm<OT,false><<<ggrid, 256, 0, stream>>>(X, Wl, OUT);                               // k=0: T0=X
    k_prop256<<<NODES, 256, 0, stream>>>(X, X, Y, 1.f,  0.f, rowptr, ccol, cw);            // T1 -> Y
    k_gemm<OT,true><<<ggrid, 256, 0, stream>>>(Y, Wl + 1*HD*HD, OUT);
    k_prop256<<<NODES, 256, 0, stream>>>(Y, X, X, 2.f, -1.f, rowptr, ccol, cw);            // T2 -> X
    k_gemm<OT,true><<<ggrid, 256, 0, stream>>>(X, Wl + 2*HD*HD, OUT);
    k_prop256<<<NODES, 256, 0, stream>>>(X, Y, Y, 2.f, -1.f, rowptr, ccol, cw);            // T3 -> Y
    k_gemm<OT,true><<<ggrid, 256, 0, stream>>>(Y, Wl + 3*HD*HD, OUT);
    k_prop256<<<NODES, 256, 0, stream>>>(Y, X, X, 2.f, -1.f, rowptr, ccol, cw);            // T4 -> X
    k_gemm<OT,true><<<ggrid, 256, 0, stream>>>(X, Wl + 4*HD*HD, OUT);
    k_prop256<<<NODES, 256, 0, stream>>>(X, Y, Y, 2.f, -1.f, rowptr, ccol, cw);            // T5 -> Y
    k_gemm<OT,true><<<ggrid, 256, 0, stream>>>(Y, Wl + 5*HD*HD, OUT);
    if (L < 2) {
      hipMemsetAsync(stats, 0, (size_t)2*HD*4, stream);
      k_bnstats<OT><<<1024, 256, 0, stream>>>(OUT, bs[L], stats);
      k_bnapply<OT><<<4096, 256, 0, stream>>>(OUT, bs[L], stats, gs[L], bes[L], X);
    } else {
      k_rownorm<OT><<<NODES/4, 256, 0, stream>>>(OUT, bs[L], X);
    }
  }

  // ---- pooling ----
  k_pool<<<NJETS, 256, 0, stream>>>(X, x, centers, log_temp, out);
}

extern "C" void kernel_launch(void* const* d_in, const int* in_sizes, int n_in,
                              void* d_out, int out_size, void* d_ws, size_t ws_size,
                              hipStream_t stream) {
  (void)in_sizes; (void)n_in; (void)out_size;
  const float* x   = (const float*)d_in[0];
  const int*   ei  = (const int*)d_in[1];
  const int*   srcA = ei;
  const int*   tgtA = ei + NEDGE;
  const float* W1  = (const float*)d_in[3];
  const float* b1  = (const float*)d_in[4];
  const float* W2  = (const float*)d_in[5];
  const float* b2  = (const float*)d_in[6];
  const float* W3  = (const float*)d_in[7];
  const float* b3  = (const float*)d_in[8];
  const float* W4  = (const float*)d_in[9];
  const float* b4  = (const float*)d_in[10];
  const float* g1  = (const float*)d_in[11];
  const float* be1 = (const float*)d_in[12];
  const float* g2  = (const float*)d_in[13];
  const float* be2 = (const float*)d_in[14];
  const float* g3  = (const float*)d_in[15];
  const float* be3 = (const float*)d_in[16];
  const float* centers  = (const float*)d_in[17];
  const float* log_temp = (const float*)d_in[18];
  float* out = (float*)d_out;

  auto rb = [](size_t b) { return (b + 255) & ~(size_t)255; };
  auto plan_bytes = [&](size_t out_esz) {
    return 2*rb((size_t)NODES*HD*2) + rb((size_t)NODES*HD*out_esz)
         + 3*rb((size_t)NODES*4) + rb((size_t)(NODES+1)*4)
         + rb((size_t)NEDGE) + rb((size_t)NEDGE*4) + rb((size_t)2*HD*4);
  };
  size_t needA = plan_bytes(4);   // fp32 OUT  (~330 MB)
  size_t needB = plan_bytes(2);   // fp16 OUT  (~251 MB)
  fprintf(stderr, "[kernel_launch] ws_size=%zu needA=%zu needB=%zu\n", ws_size, needA, needB);

  if (d_ws == nullptr || ws_size < needB) {
    // Diagnostic: encode workspace size (in MB) into the reported absmax.
    float code = 1.0e6f + (float)(ws_size >> 20);
    k_diag<<<1, 1, 0, stream>>>(out, code);
    return;
  }

  if (ws_size >= needA)
    run_plan<float>(x, srcA, tgtA, W1, b1, W2, b2, W3, b3, W4, b4,
                    g1, be1, g2, be2, g3, be3, centers, log_temp,
                    out, (char*)d_ws, stream);
  else
    run_plan<u16>(x, srcA, tgtA, W1, b1, W2, b2, W3, b3, W4, b4,
                  g1, be1, g2, be2, g3, be3, centers, log_temp,
                  out, (char*)d_ws, stream);
}

// Round 4
// 3941.386 us; speedup vs baseline: 3.8372x; 3.8372x over previous
//
#include <hip/hip_runtime.h>
#include <cstdio>

#define NODES 153600
#define PJ 150
#define NJETS 1024
#define DEG 16
#define NEDGE (NODES*DEG)
#define HD 256
#define NCL 10

typedef unsigned short u16;  // fp16 bit pattern
typedef _Float16 f16;
typedef f16 f16x8 __attribute__((ext_vector_type(8)));
typedef u16 u16x8 __attribute__((ext_vector_type(8)));
typedef float f32x4 __attribute__((ext_vector_type(4)));

__device__ inline float h2f(u16 u) { union { u16 s; f16 h; } v; v.s = u; return (float)v.h; }
__device__ inline u16 f2h(float f) { union { u16 s; f16 h; } v; v.h = (f16)f; return v.s; }

template<typename T> __device__ inline float ldv(const T* p);
template<> __device__ inline float ldv<float>(const float* p) { return *p; }
template<> __device__ inline float ldv<u16>(const u16* p) { return h2f(*p); }
template<typename T> __device__ inline void stv(T* p, float v);
template<> __device__ inline void stv<float>(float* p, float v) { *p = v; }
template<> __device__ inline void stv<u16>(u16* p, float v) { *p = f2h(v); }

// ---------------- diagnostic ----------------
__global__ void k_diag(float* out, float code) {
  if (blockIdx.x == 0 && threadIdx.x == 0) out[0] = code;
}

// ---------------- graph preprocessing ----------------

__global__ __launch_bounds__(256) void k_dis(const int* __restrict__ tgt, float* __restrict__ dis) {
  int n = blockIdx.x*256 + threadIdx.x;
  if (n >= NODES) return;
  int cnt = 0;
#pragma unroll
  for (int j = 0; j < DEG; ++j) cnt += (tgt[n*DEG + j] != n) ? 1 : 0;
  dis[n] = (cnt > 0) ? rsqrtf((float)cnt) : 0.f;
}

__global__ __launch_bounds__(256) void k_counts(const int* __restrict__ tgt, int* __restrict__ counts) {
  int e = blockIdx.x*256 + threadIdx.x;
  if (e >= NEDGE) return;
  atomicAdd(&counts[tgt[e]], 1);
}

__global__ __launch_bounds__(256) void k_scan(const int* __restrict__ counts, int* __restrict__ rowptr, int* __restrict__ cursor) {
  int j = blockIdx.x*256 + threadIdx.x;
  if (j >= NJETS) return;
  int run = j*PJ*DEG;  // jet j's target edges occupy exactly [2400j, 2400(j+1))
  for (int l = 0; l < PJ; ++l) {
    int idx = j*PJ + l;
    int cnt = counts[idx];
    rowptr[idx] = run;
    cursor[idx] = run;
    run += cnt;
  }
  if (j == 0) rowptr[NODES] = NEDGE;
}

__global__ __launch_bounds__(256) void k_fill(const int* __restrict__ src_, const int* __restrict__ tgt_,
                                              const float* __restrict__ dis, int* __restrict__ cursor,
                                              unsigned char* __restrict__ ccol, float* __restrict__ cw) {
  int e = blockIdx.x*256 + threadIdx.x;
  if (e >= NEDGE) return;
  int s = src_[e], t = tgt_[e];
  int pos = atomicAdd(&cursor[t], 1);
  ccol[pos] = (unsigned char)(s % PJ);               // jet-local src index (<150)
  cw[pos] = (s != t) ? -(dis[s]*dis[t]) : 0.f;       // scaled-Laplacian weight
}

// ---------------- layer 1 (din=3, fp32 scratch) ----------------

__global__ __launch_bounds__(256) void k_tall0(const float* __restrict__ x, float* __restrict__ tall) {
  int n = blockIdx.x*256 + threadIdx.x;
  if (n >= NODES) return;
  tall[n*18+0] = x[n*3+0]; tall[n*18+1] = x[n*3+1]; tall[n*18+2] = x[n*3+2];
}

__global__ __launch_bounds__(256) void k_prop3(const float* __restrict__ hin, const float* __restrict__ prev,
                                               float* __restrict__ out3, float* __restrict__ tallslot,
                                               float alpha, float beta,
                                               const int* __restrict__ rowptr, const unsigned char* __restrict__ ccol,
                                               const float* __restrict__ cw) {
  int t = blockIdx.x*256 + threadIdx.x;
  if (t >= NODES) return;
  int jb = (t/PJ)*PJ;
  int rs = rowptr[t], re = rowptr[t+1];
  float a0=0.f, a1=0.f, a2=0.f;
  for (int e = rs; e < re; ++e) {
    float w = cw[e];
    int s = (jb + (int)ccol[e])*3;
    a0 += w*hin[s]; a1 += w*hin[s+1]; a2 += w*hin[s+2];
  }
  float o0 = alpha*a0, o1 = alpha*a1, o2 = alpha*a2;
  if (beta != 0.f) { o0 += beta*prev[t*3]; o1 += beta*prev[t*3+1]; o2 += beta*prev[t*3+2]; }
  out3[t*3]=o0; out3[t*3+1]=o1; out3[t*3+2]=o2;
  tallslot[t*18]=o0; tallslot[t*18+1]=o1; tallslot[t*18+2]=o2;
}

// out[n,c] = sum_{i<18} Tall[n,i] * W1[i,c]   (W1 flat (6,3,256) == (18,256))
template<typename OT>
__global__ __launch_bounds__(256) void k_gemm1(const float* __restrict__ tall, const float* __restrict__ W1,
                                               OT* __restrict__ outc) {
  __shared__ float wl[18*256];
  __shared__ float tl[64*18];
  int c = threadIdx.x;
  for (int i = c; i < 18*256; i += 256) wl[i] = W1[i];
  int n0 = blockIdx.x*64;
  __syncthreads();
  for (int i = c; i < 64*18; i += 256) tl[i] = tall[(size_t)n0*18 + i];
  __syncthreads();
  for (int n = 0; n < 64; ++n) {
    float acc = 0.f;
#pragma unroll
    for (int i = 0; i < 18; ++i) acc += tl[n*18 + i] * wl[i*256 + c];
    stv(&outc[(size_t)(n0+n)*HD + c], acc);
  }
}

// ---------------- per-jet LDS-staged prop on 256 channels ----------------
// out[t,c] = alpha * sum_{edges->t} w * h[src,c] + beta * prev[t,c]   (prev in-place OK)
__global__ __launch_bounds__(512) void k_prop_jet(const u16* __restrict__ h, const u16* __restrict__ prev,
                                                  u16* __restrict__ outp, float alpha, float beta,
                                                  const int* __restrict__ rowptr, const unsigned char* __restrict__ ccol,
                                                  const float* __restrict__ cw) {
  __shared__ u16 hs[PJ*128];          // one channel-half of the jet's h tile (38.4 KB)
  int j = blockIdx.x, tid = threadIdx.x;
  int jb = j * PJ;
  int cg = tid & 15, rslot = tid >> 4;  // 16 channel-groups x 32 row-slots
  for (int half = 0; half < 2; ++half) {
    if (half) __syncthreads();          // prior compute done before restage
    for (int i = tid; i < PJ*16; i += 512) {
      int row = i >> 4, q = i & 15;
      *(u16x8*)&hs[row*128 + q*8] = *(const u16x8*)&h[(size_t)(jb+row)*HD + half*128 + q*8];
    }
    __syncthreads();
    int c0 = half*128 + cg*8;
    for (int r = rslot; r < PJ; r += 32) {
      int node = jb + r;
      int rs = rowptr[node], re = rowptr[node+1];
      float acc[8] = {};
      for (int e = rs; e < re; ++e) {
        float w = cw[e];
        int col = (int)ccol[e];
        u16x8 v = *(const u16x8*)&hs[col*128 + cg*8];
#pragma unroll
        for (int q = 0; q < 8; ++q) acc[q] += w * h2f(v[q]);
      }
      u16x8 o;
      if (beta != 0.f) {
        u16x8 pv = *(const u16x8*)&prev[(size_t)node*HD + c0];
#pragma unroll
        for (int q = 0; q < 8; ++q) o[q] = f2h(alpha*acc[q] + beta*h2f(pv[q]));
      } else {
#pragma unroll
        for (int q = 0; q < 8; ++q) o[q] = f2h(alpha*acc[q]);
      }
      *(u16x8*)&outp[(size_t)node*HD + c0] = o;
    }
  }
}

// ---------------- MFMA GEMM: C[M,256] (+)= A[M,256](fp16) @ W[256,256](fp32 via f16 hi/lo) ---------
// Tile 128x64, 4 waves (2x2), BK=32, v_mfma_f32_16x16x32_f16.
// W split: Whi = f16(W); Wlo = f16((W - Whi)*2048)  -> C = accH + accL/2048 (22-bit W mantissa).
// A/B fragments use consistent k-mapping (lane-group,elem)->k: bijection => correct dot product.
// C/D layout (HW-verified): col = lane&15, row = (lane>>4)*4 + reg.

template<typename OT, bool ACCUM>
__global__ __launch_bounds__(256) void k_gemm(const u16* __restrict__ A, const float* __restrict__ Wm,
                                              OT* __restrict__ C) {
  __shared__ f16 Al[128*40];    // A tile [128][32] padded to 40 (bank-conflict-free)
  __shared__ f16 Wh[64*40];     // W^T hi  [n][k]
  __shared__ f16 Wl[64*40];     // W^T lo  [n][k], scaled by 2048
  int tid = threadIdx.x;
  int lane = tid & 63, wid = tid >> 6;
  int wm = wid >> 1, wn = wid & 1;
  int lr = lane & 15, lg = lane >> 4;
  int m0 = blockIdx.x * 128, n0 = blockIdx.y * 64;
  f32x4 accH[4][2] = {{{0.f,0.f,0.f,0.f}}};
  f32x4 accL[4][2] = {{{0.f,0.f,0.f,0.f}}};
#pragma unroll
  for (int mf = 0; mf < 4; ++mf)
#pragma unroll
    for (int nf = 0; nf < 2; ++nf) { accH[mf][nf] = (f32x4)0.f; accL[mf][nf] = (f32x4)0.f; }

  const f16* Af = (const f16*)A;
  int sa_row = tid >> 1;                 // staging helpers
  for (int k0 = 0; k0 < 256; k0 += 32) {
    __syncthreads();
    // stage A: 128 rows x 32 f16 = 512 chunks of 8
    for (int i = tid; i < 512; i += 256) {
      int row = i >> 2, q = i & 3;
      f16x8 v = *(const f16x8*)&Af[(size_t)(m0+row)*HD + k0 + q*8];
      *(f16x8*)&Al[row*40 + q*8] = v;
    }
    // stage W^T hi/lo: thread: n = tid&63, kg = tid>>6 (8 k's each)
    {
      int n = tid & 63, kg = tid >> 6;
      f16x8 hv, lv;
#pragma unroll
      for (int q = 0; q < 8; ++q) {
        float w = Wm[(size_t)(k0 + kg*8 + q)*256 + n0 + n];
        f16 hi = (f16)w;
        hv[q] = hi;
        lv[q] = (f16)((w - (float)hi) * 2048.0f);
      }
      *(f16x8*)&Wh[n*40 + kg*8] = hv;
      *(f16x8*)&Wl[n*40 + kg*8] = lv;
    }
    __syncthreads();
    f16x8 a[4], bh[2], bl[2];
#pragma unroll
    for (int mf = 0; mf < 4; ++mf)
      a[mf] = *(const f16x8*)&Al[(wm*64 + mf*16 + lr)*40 + lg*8];
#pragma unroll
    for (int nf = 0; nf < 2; ++nf) {
      bh[nf] = *(const f16x8*)&Wh[(wn*32 + nf*16 + lr)*40 + lg*8];
      bl[nf] = *(const f16x8*)&Wl[(wn*32 + nf*16 + lr)*40 + lg*8];
    }
#pragma unroll
    for (int mf = 0; mf < 4; ++mf)
#pragma unroll
      for (int nf = 0; nf < 2; ++nf) {
        accH[mf][nf] = __builtin_amdgcn_mfma_f32_16x16x32_f16(a[mf], bh[nf], accH[mf][nf], 0, 0, 0);
        accL[mf][nf] = __builtin_amdgcn_mfma_f32_16x16x32_f16(a[mf], bl[nf], accL[mf][nf], 0, 0, 0);
      }
  }
  (void)sa_row;
  const float s = 1.0f / 2048.0f;
#pragma unroll
  for (int mf = 0; mf < 4; ++mf)
#pragma unroll
    for (int nf = 0; nf < 2; ++nf)
#pragma unroll
      for (int e = 0; e < 4; ++e) {
        int row = m0 + wm*64 + mf*16 + lg*4 + e;
        int col = n0 + wn*32 + nf*16 + lr;
        float v = accH[mf][nf][e] + accL[mf][nf][e]*s;
        OT* p = &C[(size_t)row*HD + col];
        if (ACCUM) v += ldv(p);
        stv(p, v);
      }
}

// ---------------- batchnorm (training stats, biased var) + leaky relu ----------------

template<typename OT>
__global__ __launch_bounds__(256) void k_bnstats(const OT* __restrict__ Cc, const float* __restrict__ bias,
                                                 float* __restrict__ stats) {
  int c = threadIdx.x;
  float bc = bias[c];
  float s = 0.f, s2 = 0.f;
  int rows_per = (NODES + gridDim.x - 1) / gridDim.x;
  int r0 = blockIdx.x * rows_per;
  int r1 = min(NODES, r0 + rows_per);
  for (int r = r0; r < r1; ++r) {
    float v = ldv(&Cc[(size_t)r*HD + c]) + bc;
    s += v; s2 += v*v;
  }
  atomicAdd(&stats[c], s);
  atomicAdd(&stats[HD + c], s2);
}

template<typename OT>
__global__ __launch_bounds__(256) void k_bnapply(const OT* __restrict__ Cc, const float* __restrict__ bias,
                                                 const float* __restrict__ stats, const float* __restrict__ g,
                                                 const float* __restrict__ be, u16* __restrict__ hout) {
  const float invN = 1.f/(float)NODES;
  int total = NODES*HD;
  for (int i = blockIdx.x*256 + threadIdx.x; i < total; i += gridDim.x*256) {
    int c = i & (HD-1);
    float m = stats[c]*invN;
    float v = stats[HD+c]*invN - m*m;
    float wq = rsqrtf(v + 1e-5f);
    float val = (ldv(&Cc[i]) + bias[c] - m)*wq*g[c] + be[c];
    hout[i] = f2h((val > 0.f) ? val : 0.01f*val);
  }
}

// ---------------- row L2 normalize (layer 4 output) ----------------

template<typename OT>
__global__ __launch_bounds__(256) void k_rownorm(const OT* __restrict__ Cc, const float* __restrict__ bias,
                                                 u16* __restrict__ hout) {
  int wave = threadIdx.x >> 6, lane = threadIdx.x & 63;
  int n = blockIdx.x*4 + wave;
  float v0 = ldv(&Cc[(size_t)n*HD + lane*4 + 0]) + bias[lane*4 + 0];
  float v1 = ldv(&Cc[(size_t)n*HD + lane*4 + 1]) + bias[lane*4 + 1];
  float v2 = ldv(&Cc[(size_t)n*HD + lane*4 + 2]) + bias[lane*4 + 2];
  float v3 = ldv(&Cc[(size_t)n*HD + lane*4 + 3]) + bias[lane*4 + 3];
  float ss = v0*v0 + v1*v1 + v2*v2 + v3*v3;
  for (int off = 32; off > 0; off >>= 1) ss += __shfl_down(ss, off, 64);
  ss = __shfl(ss, 0, 64);
  float inv = 1.f / fmaxf(sqrtf(ss), 1e-12f);
  hout[(size_t)n*HD + lane*4 + 0] = f2h(v0*inv);
  hout[(size_t)n*HD + lane*4 + 1] = f2h(v1*inv);
  hout[(size_t)n*HD + lane*4 + 2] = f2h(v2*inv);
  hout[(size_t)n*HD + lane*4 + 3] = f2h(v3*inv);
}

// ---------------- distance softmax pooling ----------------

__global__ __launch_bounds__(256) void k_pool(const u16* __restrict__ h, const float* __restrict__ x,
                                              const float* __restrict__ centers, const float* __restrict__ log_temp,
                                              float* __restrict__ out) {
  __shared__ float a_s[PJ][NCL];
  __shared__ float colsum[NCL];
  int j = blockIdx.x;
  int tid = threadIdx.x;
  float T = expf(fminf(fmaxf(log_temp[0], -2.f), 3.f));
  if (tid < PJ) {
    int g = j*PJ + tid;
    float eta = x[(size_t)g*3], phi = x[(size_t)g*3 + 1];
    float d[NCL];
    float dmin = 1e30f;
#pragma unroll
    for (int k = 0; k < NCL; ++k) {
      float dx = eta - centers[2*k], dy = phi - centers[2*k+1];
      d[k] = dx*dx + dy*dy;
      dmin = fminf(dmin, d[k]);
    }
    float s = 0.f, ek[NCL];
#pragma unroll
    for (int k = 0; k < NCL; ++k) { ek[k] = expf(-T*(d[k]-dmin)); s += ek[k]; }
    float invs = 1.f/s;
#pragma unroll
    for (int k = 0; k < NCL; ++k) a_s[tid][k] = ek[k]*invs;
  }
  __syncthreads();
  if (tid < NCL) {   // deterministic column sums
    float s = 0.f;
    for (int n = 0; n < PJ; ++n) s += a_s[n][tid];
    colsum[tid] = s;
  }
  __syncthreads();
  int c = tid;
  float acc[NCL] = {};
  for (int n = 0; n < PJ; ++n) {
    float hv = h2f(h[(size_t)(j*PJ + n)*HD + c]);
#pragma unroll
    for (int k = 0; k < NCL; ++k) acc[k] += a_s[n][k]*hv;
  }
#pragma unroll
  for (int k = 0; k < NCL; ++k)
    out[(size_t)j*(NCL*HD) + k*HD + c] = acc[k] / (colsum[k] + 1e-8f);
}

// ---------------- host ----------------

template<typename OT>
static void run_plan(const float* x, const int* srcA, const int* tgtA,
                     const float* W1, const float* b1, const float* W2, const float* b2,
                     const float* W3, const float* b3, const float* W4, const float* b4,
                     const float* g1, const float* be1, const float* g2, const float* be2,
                     const float* g3, const float* be3, const float* centers, const float* log_temp,
                     float* out, char* wp0, hipStream_t stream) {
  char* wp = wp0;
  auto alloc = [&](size_t b) -> void* {
    void* p = (void*)wp;
    wp += (b + 255) & ~(size_t)255;
    return p;
  };
  u16*   X    = (u16*)alloc((size_t)NODES*HD*2);
  u16*   Y    = (u16*)alloc((size_t)NODES*HD*2);
  OT*    OUT  = (OT*)alloc((size_t)NODES*HD*sizeof(OT));
  float* dis  = (float*)alloc((size_t)NODES*4);
  int*   counts = (int*)alloc((size_t)NODES*4);
  int*   cursor = (int*)alloc((size_t)NODES*4);
  int*   rowptr = (int*)alloc((size_t)(NODES+1)*4);
  unsigned char* ccol = (unsigned char*)alloc((size_t)NEDGE);
  float* cw     = (float*)alloc((size_t)NEDGE*4);
  float* stats  = (float*)alloc((size_t)2*HD*4);
  // layer-1 fp32 scratch aliases into Y (Y first written at layer-2 T1 prop)
  float* Tall = (float*)Y;
  float* t3a  = Tall + (size_t)NODES*18;
  float* t3b  = t3a + (size_t)NODES*3;

  // graph preprocessing
  hipMemsetAsync(counts, 0, (size_t)NODES*4, stream);
  k_dis<<<(NODES+255)/256, 256, 0, stream>>>(tgtA, dis);
  k_counts<<<(NEDGE+255)/256, 256, 0, stream>>>(tgtA, counts);
  k_scan<<<(NJETS+255)/256, 256, 0, stream>>>(counts, rowptr, cursor);
  k_fill<<<(NEDGE+255)/256, 256, 0, stream>>>(srcA, tgtA, dis, cursor, ccol, cw);

  const int NB = (NODES+255)/256;

  // ---- layer 1 (din=3) ----
  k_tall0<<<NB, 256, 0, stream>>>(x, Tall);
  k_prop3<<<NB, 256, 0, stream>>>(x,   x,   t3a, Tall+3,  1.f,  0.f, rowptr, ccol, cw);  // T1
  k_prop3<<<NB, 256, 0, stream>>>(t3a, x,   t3b, Tall+6,  2.f, -1.f, rowptr, ccol, cw);  // T2
  k_prop3<<<NB, 256, 0, stream>>>(t3b, t3a, t3a, Tall+9,  2.f, -1.f, rowptr, ccol, cw);  // T3
  k_prop3<<<NB, 256, 0, stream>>>(t3a, t3b, t3b, Tall+12, 2.f, -1.f, rowptr, ccol, cw);  // T4
  k_prop3<<<NB, 256, 0, stream>>>(t3b, t3a, t3a, Tall+15, 2.f, -1.f, rowptr, ccol, cw);  // T5
  k_gemm1<OT><<<NODES/64, 256, 0, stream>>>(Tall, W1, OUT);
  hipMemsetAsync(stats, 0, (size_t)2*HD*4, stream);
  k_bnstats<OT><<<1024, 256, 0, stream>>>(OUT, b1, stats);
  k_bnapply<OT><<<4096, 256, 0, stream>>>(OUT, b1, stats, g1, be1, X);

  // ---- layers 2..4 (din=256) ----
  const float* Ws[3]  = {W2, W3, W4};
  const float* bs[3]  = {b2, b3, b4};
  const float* gs[2]  = {g2, g3};
  const float* bes[2] = {be2, be3};
  dim3 ggrid(NODES/128, HD/64);
  for (int L = 0; L < 3; ++L) {
    const float* Wl = Ws[L];
    k_gemm<OT,false><<<ggrid, 256, 0, stream>>>(X, Wl, OUT);                               // k=0: T0=X
    k_prop_jet<<<NJETS, 512, 0, stream>>>(X, X, Y, 1.f,  0.f, rowptr, ccol, cw);           // T1 -> Y
    k_gemm<OT,true><<<ggrid, 256, 0, stream>>>(Y, Wl + 1*HD*HD, OUT);
    k_prop_jet<<<NJETS, 512, 0, stream>>>(Y, X, X, 2.f, -1.f, rowptr, ccol, cw);           // T2 -> X
    k_gemm<OT,true><<<ggrid, 256, 0, stream>>>(X, Wl + 2*HD*HD, OUT);
    k_prop_jet<<<NJETS, 512, 0, stream>>>(X, Y, Y, 2.f, -1.f, rowptr, ccol, cw);           // T3 -> Y
    k_gemm<OT,true><<<ggrid, 256, 0, stream>>>(Y, Wl + 3*HD*HD, OUT);
    k_prop_jet<<<NJETS, 512, 0, stream>>>(Y, X, X, 2.f, -1.f, rowptr, ccol, cw);           // T4 -> X
    k_gemm<OT,true><<<ggrid, 256, 0, stream>>>(X, Wl + 4*HD*HD, OUT);
    k_prop_jet<<<NJETS, 512, 0, stream>>>(X, Y, Y, 2.f, -1.f, rowptr, ccol, cw);           // T5 -> Y
    k_gemm<OT,true><<<ggrid, 256, 0, stream>>>(Y, Wl + 5*HD*HD, OUT);
    if (L < 2) {
      hipMemsetAsync(stats, 0, (size_t)2*HD*4, stream);
      k_bnstats<OT><<<1024, 256, 0, stream>>>(OUT, bs[L], stats);
      k_bnapply<OT><<<4096, 256, 0, stream>>>(OUT, bs[L], stats, gs[L], bes[L], X);
    } else {
      k_rownorm<OT><<<NODES/4, 256, 0, stream>>>(OUT, bs[L], X);
    }
  }

  // ---- pooling ----
  k_pool<<<NJETS, 256, 0, stream>>>(X, x, centers, log_temp, out);
}

extern "C" void kernel_launch(void* const* d_in, const int* in_sizes, int n_in,
                              void* d_out, int out_size, void* d_ws, size_t ws_size,
                              hipStream_t stream) {
  (void)in_sizes; (void)n_in; (void)out_size;
  const float* x   = (const float*)d_in[0];
  const int*   ei  = (const int*)d_in[1];
  const int*   srcA = ei;
  const int*   tgtA = ei + NEDGE;
  const float* W1  = (const float*)d_in[3];
  const float* b1  = (const float*)d_in[4];
  const float* W2  = (const float*)d_in[5];
  const float* b2  = (const float*)d_in[6];
  const float* W3  = (const float*)d_in[7];
  const float* b3  = (const float*)d_in[8];
  const float* W4  = (const float*)d_in[9];
  const float* b4  = (const float*)d_in[10];
  const float* g1  = (const float*)d_in[11];
  const float* be1 = (const float*)d_in[12];
  const float* g2  = (const float*)d_in[13];
  const float* be2 = (const float*)d_in[14];
  const float* g3  = (const float*)d_in[15];
  const float* be3 = (const float*)d_in[16];
  const float* centers  = (const float*)d_in[17];
  const float* log_temp = (const float*)d_in[18];
  float* out = (float*)d_out;

  auto rb = [](size_t b) { return (b + 255) & ~(size_t)255; };
  auto plan_bytes = [&](size_t out_esz) {
    return 2*rb((size_t)NODES*HD*2) + rb((size_t)NODES*HD*out_esz)
         + 3*rb((size_t)NODES*4) + rb((size_t)(NODES+1)*4)
         + rb((size_t)NEDGE) + rb((size_t)NEDGE*4) + rb((size_t)2*HD*4);
  };
  size_t needA = plan_bytes(4);   // fp32 OUT  (~330 MB)
  size_t needB = plan_bytes(2);   // fp16 OUT  (~251 MB)
  fprintf(stderr, "[kernel_launch] ws_size=%zu needA=%zu needB=%zu\n", ws_size, needA, needB);

  if (d_ws == nullptr || ws_size < needB) {
    // Diagnostic: encode workspace size (in MB) into the reported absmax.
    float code = 1.0e6f + (float)(ws_size >> 20);
    k_diag<<<1, 1, 0, stream>>>(out, code);
    return;
  }

  if (ws_size >= needA)
    run_plan<float>(x, srcA, tgtA, W1, b1, W2, b2, W3, b3, W4, b4,
                    g1, be1, g2, be2, g3, be3, centers, log_temp,
                    out, (char*)d_ws, stream);
  else
    run_plan<u16>(x, srcA, tgtA, W1, b1, W2, b2, W3, b3, W4, b4,
                  g1, be1, g2, be2, g3, be3, centers, log_temp,
                  out, (char*)d_ws, stream);
}

// Round 5
// 3084.170 us; speedup vs baseline: 4.9037x; 1.2779x over previous
//
#include <hip/hip_runtime.h>
#include <cstdio>

#define NODES 153600
#define PJ 150
#define NJETS 1024
#define DEG 16
#define NEDGE (NODES*DEG)
#define HD 256
#define NCL 10

typedef unsigned short u16;  // fp16 bit pattern
typedef _Float16 f16;
typedef f16 f16x8 __attribute__((ext_vector_type(8)));
typedef u16 u16x8 __attribute__((ext_vector_type(8)));
typedef float f32x4 __attribute__((ext_vector_type(4)));

__device__ inline float h2f(u16 u) { union { u16 s; f16 h; } v; v.s = u; return (float)v.h; }
__device__ inline u16 f2h(float f) { union { u16 s; f16 h; } v; v.h = (f16)f; return v.s; }

template<typename T> __device__ inline float ldv(const T* p);
template<> __device__ inline float ldv<float>(const float* p) { return *p; }
template<> __device__ inline float ldv<u16>(const u16* p) { return h2f(*p); }
template<typename T> __device__ inline void stv(T* p, float v);
template<> __device__ inline void stv<float>(float* p, float v) { *p = v; }
template<> __device__ inline void stv<u16>(u16* p, float v) { *p = f2h(v); }

// ---------------- diagnostic ----------------
__global__ void k_diag(float* out, float code) {
  if (blockIdx.x == 0 && threadIdx.x == 0) out[0] = code;
}

// ---------------- graph preprocessing ----------------

__global__ __launch_bounds__(256) void k_dis(const int* __restrict__ tgt, float* __restrict__ dis) {
  int n = blockIdx.x*256 + threadIdx.x;
  if (n >= NODES) return;
  int cnt = 0;
#pragma unroll
  for (int j = 0; j < DEG; ++j) cnt += (tgt[n*DEG + j] != n) ? 1 : 0;
  dis[n] = (cnt > 0) ? rsqrtf((float)cnt) : 0.f;
}

__global__ __launch_bounds__(256) void k_counts(const int* __restrict__ tgt, int* __restrict__ counts) {
  int e = blockIdx.x*256 + threadIdx.x;
  if (e >= NEDGE) return;
  atomicAdd(&counts[tgt[e]], 1);
}

__global__ __launch_bounds__(256) void k_scan(const int* __restrict__ counts, int* __restrict__ rowptr, int* __restrict__ cursor) {
  int j = blockIdx.x*256 + threadIdx.x;
  if (j >= NJETS) return;
  int run = j*PJ*DEG;  // jet j's target edges occupy exactly [2400j, 2400(j+1))
  for (int l = 0; l < PJ; ++l) {
    int idx = j*PJ + l;
    int cnt = counts[idx];
    rowptr[idx] = run;
    cursor[idx] = run;
    run += cnt;
  }
  if (j == 0) rowptr[NODES] = NEDGE;
}

__global__ __launch_bounds__(256) void k_fill(const int* __restrict__ src_, const int* __restrict__ tgt_,
                                              const float* __restrict__ dis, int* __restrict__ cursor,
                                              unsigned char* __restrict__ ccol, float* __restrict__ cw) {
  int e = blockIdx.x*256 + threadIdx.x;
  if (e >= NEDGE) return;
  int s = src_[e], t = tgt_[e];
  int pos = atomicAdd(&cursor[t], 1);
  ccol[pos] = (unsigned char)(s % PJ);               // jet-local src index (<150)
  cw[pos] = (s != t) ? -(dis[s]*dis[t]) : 0.f;       // scaled-Laplacian weight
}

// ---------------- layer 1 (din=3, fp32 scratch) ----------------

__global__ __launch_bounds__(256) void k_tall0(const float* __restrict__ x, float* __restrict__ tall) {
  int n = blockIdx.x*256 + threadIdx.x;
  if (n >= NODES) return;
  tall[n*18+0] = x[n*3+0]; tall[n*18+1] = x[n*3+1]; tall[n*18+2] = x[n*3+2];
}

__global__ __launch_bounds__(256) void k_prop3(const float* __restrict__ hin, const float* __restrict__ prev,
                                               float* __restrict__ out3, float* __restrict__ tallslot,
                                               float alpha, float beta,
                                               const int* __restrict__ rowptr, const unsigned char* __restrict__ ccol,
                                               const float* __restrict__ cw) {
  int t = blockIdx.x*256 + threadIdx.x;
  if (t >= NODES) return;
  int jb = (t/PJ)*PJ;
  int rs = rowptr[t], re = rowptr[t+1];
  float a0=0.f, a1=0.f, a2=0.f;
  for (int e = rs; e < re; ++e) {
    float w = cw[e];
    int s = (jb + (int)ccol[e])*3;
    a0 += w*hin[s]; a1 += w*hin[s+1]; a2 += w*hin[s+2];
  }
  float o0 = alpha*a0, o1 = alpha*a1, o2 = alpha*a2;
  if (beta != 0.f) { o0 += beta*prev[t*3]; o1 += beta*prev[t*3+1]; o2 += beta*prev[t*3+2]; }
  out3[t*3]=o0; out3[t*3+1]=o1; out3[t*3+2]=o2;
  tallslot[t*18]=o0; tallslot[t*18+1]=o1; tallslot[t*18+2]=o2;
}

// out[n,c] = sum_{i<18} Tall[n,i] * W1[i,c]   (W1 flat (6,3,256) == (18,256))
template<typename OT>
__global__ __launch_bounds__(256) void k_gemm1(const float* __restrict__ tall, const float* __restrict__ W1,
                                               OT* __restrict__ outc) {
  __shared__ float wl[18*256];
  __shared__ float tl[64*18];
  int c = threadIdx.x;
  for (int i = c; i < 18*256; i += 256) wl[i] = W1[i];
  int n0 = blockIdx.x*64;
  __syncthreads();
  for (int i = c; i < 64*18; i += 256) tl[i] = tall[(size_t)n0*18 + i];
  __syncthreads();
  for (int n = 0; n < 64; ++n) {
    float acc = 0.f;
#pragma unroll
    for (int i = 0; i < 18; ++i) acc += tl[n*18 + i] * wl[i*256 + c];
    stv(&outc[(size_t)(n0+n)*HD + c], acc);
  }
}

// ---------------- W prep: WT[cout][k] f16, k = term*256 + cin ----------------
__global__ __launch_bounds__(256) void k_prepW(const float* __restrict__ W, u16* __restrict__ WT) {
  int i = blockIdx.x*256 + threadIdx.x;     // over 256*1536
  if (i >= 256*1536) return;
  int cout = i / 1536, k = i - cout*1536;
  int term = k >> 8, cin = k & 255;
  WT[i] = f2h(W[(size_t)term*65536 + cin*256 + cout]);
}

// ---------------- fused per-jet Chebyshev layer ----------------
// Block = one jet (512 thr, 8 waves 2x4). LDS holds the T-recurrence ping-pong
// tiles for a 64-channel quarter; MFMA accumulates out = sum_t T_t @ W_t across
// all 6 terms x 4 quarters into persistent registers. Props (VALU) interleave
// with MFMA per term. A/B frags share the (lg,elem)->k bijection (validated r4);
// C/D layout: col = lane&15, row = (lane>>4)*4 + reg (HW-verified).
template<typename OT>
__global__ __launch_bounds__(512) void k_cheb(const u16* __restrict__ X, const u16* __restrict__ WTu,
                                              OT* __restrict__ OUTp,
                                              const int* __restrict__ rowptr,
                                              const unsigned char* __restrict__ ccol,
                                              const float* __restrict__ cw) {
  __shared__ f16 Ta[160*72];      // [row][64ch + 8 pad]
  __shared__ f16 Tb[160*72];
  __shared__ float cw_s[PJ*DEG];
  __shared__ u16 col_s[PJ*DEG];
  __shared__ int rp_s[PJ+1];
  const f16* WT = (const f16*)WTu;
  int j = blockIdx.x, tid = threadIdx.x;
  int jb = j*PJ, e0 = j*PJ*DEG;
  for (int i = tid; i < PJ*DEG; i += 512) { cw_s[i] = cw[e0+i]; col_s[i] = (u16)ccol[e0+i]; }
  for (int i = tid; i < PJ+1; i += 512) rp_s[i] = rowptr[jb+i] - e0;
  for (int i = tid; i < 10*64; i += 512) {          // zero pad rows 150..159
    int r = 150 + (i>>6), c = i & 63;
    Ta[r*72 + c] = (f16)0.f; Tb[r*72 + c] = (f16)0.f;
  }
  int lane = tid & 63, wid = tid >> 6;
  int wm = wid >> 2, wn = wid & 3;                  // 2(M) x 4(N) waves
  int lr = lane & 15, lg = lane >> 4;
  int cg = tid & 7, rs0 = tid >> 3;                 // prop: 8 ch-groups x 64 row-slots
  f32x4 acc[5][4];
#pragma unroll
  for (int a = 0; a < 5; ++a)
#pragma unroll
    for (int b = 0; b < 4; ++b) acc[a][b] = (f32x4)0.f;

  for (int q = 0; q < 4; ++q) {
    // stage T0 = X[:, q*64 .. q*64+63]   (previous quarter's reads fenced by t=5 sync)
    for (int i = tid; i < PJ*8; i += 512) {
      int row = i >> 3, seg = i & 7;
      *(u16x8*)&Ta[row*72 + seg*8] = *(const u16x8*)&X[(size_t)(jb+row)*HD + q*64 + seg*8];
    }
    __syncthreads();
    f16* cur = Ta; f16* oth = Tb;
#pragma unroll 1
    for (int t = 0; t < 6; ++t) {
      int kbase = t*256 + q*64;
      // --- GEMM: acc += cur @ WT[:, kbase..kbase+63] ---
#pragma unroll
      for (int ks = 0; ks < 64; ks += 32) {
        f16x8 a[5], bv[4];
#pragma unroll
        for (int nf = 0; nf < 4; ++nf)
          bv[nf] = *(const f16x8*)&WT[(size_t)(wn*64 + nf*16 + lr)*1536 + kbase + ks + lg*8];
#pragma unroll
        for (int mf = 0; mf < 5; ++mf)
          a[mf] = *(const f16x8*)&cur[(wm*80 + mf*16 + lr)*72 + ks + lg*8];
#pragma unroll
        for (int nf = 0; nf < 4; ++nf)
#pragma unroll
          for (int mf = 0; mf < 5; ++mf)
            acc[mf][nf] = __builtin_amdgcn_mfma_f32_16x16x32_f16(a[mf], bv[nf], acc[mf][nf], 0, 0, 0);
      }
      // --- prop: T_{t+1} = (t==0 ? L*T0 : 2*L*T_t - T_{t-1}) into oth ---
      if (t < 5) {
        for (int r = rs0; r < PJ; r += 64) {
          int es = rp_s[r], ee = rp_s[r+1];
          float pa[8] = {};
          for (int e = es; e < ee; ++e) {
            float w = cw_s[e];
            u16x8 v = *(const u16x8*)&cur[(int)col_s[e]*72 + cg*8];
#pragma unroll
            for (int u2 = 0; u2 < 8; ++u2) pa[u2] += w * h2f(v[u2]);
          }
          u16x8 o;
          if (t == 0) {
#pragma unroll
            for (int u2 = 0; u2 < 8; ++u2) o[u2] = f2h(pa[u2]);
          } else {
            u16x8 pv = *(const u16x8*)&oth[r*72 + cg*8];
#pragma unroll
            for (int u2 = 0; u2 < 8; ++u2) o[u2] = f2h(2.f*pa[u2] - h2f(pv[u2]));
          }
          *(u16x8*)&oth[r*72 + cg*8] = o;
        }
      }
      __syncthreads();
      f16* tmp = cur; cur = oth; oth = tmp;
    }
  }
  // epilogue: C write (rows >= 150 dropped)
#pragma unroll
  for (int mf = 0; mf < 5; ++mf) {
    int row = wm*80 + mf*16 + lg*4;
#pragma unroll
    for (int e = 0; e < 4; ++e) {
      int r = row + e;
      if (r < PJ) {
#pragma unroll
        for (int nf = 0; nf < 4; ++nf) {
          int col = wn*64 + nf*16 + lr;
          stv(&OUTp[(size_t)(jb+r)*HD + col], acc[mf][nf][e]);
        }
      }
    }
  }
}

// ---------------- batchnorm (training stats, biased var) + leaky relu ----------------

template<typename OT>
__global__ __launch_bounds__(256) void k_bnstats(const OT* __restrict__ Cc, const float* __restrict__ bias,
                                                 float* __restrict__ stats) {
  int c = threadIdx.x;
  float bc = bias[c];
  float s = 0.f, s2 = 0.f;
  int rows_per = (NODES + gridDim.x - 1) / gridDim.x;
  int r0 = blockIdx.x * rows_per;
  int r1 = min(NODES, r0 + rows_per);
  for (int r = r0; r < r1; ++r) {
    float v = ldv(&Cc[(size_t)r*HD + c]) + bc;
    s += v; s2 += v*v;
  }
  atomicAdd(&stats[c], s);
  atomicAdd(&stats[HD + c], s2);
}

template<typename OT>
__global__ __launch_bounds__(256) void k_bnapply(const OT* __restrict__ Cc, const float* __restrict__ bias,
                                                 const float* __restrict__ stats, const float* __restrict__ g,
                                                 const float* __restrict__ be, u16* __restrict__ hout) {
  const float invN = 1.f/(float)NODES;
  int total = NODES*HD;
  for (int i = blockIdx.x*256 + threadIdx.x; i < total; i += gridDim.x*256) {
    int c = i & (HD-1);
    float m = stats[c]*invN;
    float v = stats[HD+c]*invN - m*m;
    float wq = rsqrtf(v + 1e-5f);
    float val = (ldv(&Cc[i]) + bias[c] - m)*wq*g[c] + be[c];
    hout[i] = f2h((val > 0.f) ? val : 0.01f*val);
  }
}

// ---------------- row L2 normalize (layer 4 output) ----------------

template<typename OT>
__global__ __launch_bounds__(256) void k_rownorm(const OT* __restrict__ Cc, const float* __restrict__ bias,
                                                 u16* __restrict__ hout) {
  int wave = threadIdx.x >> 6, lane = threadIdx.x & 63;
  int n = blockIdx.x*4 + wave;
  float v0 = ldv(&Cc[(size_t)n*HD + lane*4 + 0]) + bias[lane*4 + 0];
  float v1 = ldv(&Cc[(size_t)n*HD + lane*4 + 1]) + bias[lane*4 + 1];
  float v2 = ldv(&Cc[(size_t)n*HD + lane*4 + 2]) + bias[lane*4 + 2];
  float v3 = ldv(&Cc[(size_t)n*HD + lane*4 + 3]) + bias[lane*4 + 3];
  float ss = v0*v0 + v1*v1 + v2*v2 + v3*v3;
  for (int off = 32; off > 0; off >>= 1) ss += __shfl_down(ss, off, 64);
  ss = __shfl(ss, 0, 64);
  float inv = 1.f / fmaxf(sqrtf(ss), 1e-12f);
  hout[(size_t)n*HD + lane*4 + 0] = f2h(v0*inv);
  hout[(size_t)n*HD + lane*4 + 1] = f2h(v1*inv);
  hout[(size_t)n*HD + lane*4 + 2] = f2h(v2*inv);
  hout[(size_t)n*HD + lane*4 + 3] = f2h(v3*inv);
}

// ---------------- distance softmax pooling ----------------

__global__ __launch_bounds__(256) void k_pool(const u16* __restrict__ h, const float* __restrict__ x,
                                              const float* __restrict__ centers, const float* __restrict__ log_temp,
                                              float* __restrict__ out) {
  __shared__ float a_s[PJ][NCL];
  __shared__ float colsum[NCL];
  int j = blockIdx.x;
  int tid = threadIdx.x;
  float T = expf(fminf(fmaxf(log_temp[0], -2.f), 3.f));
  if (tid < PJ) {
    int g = j*PJ + tid;
    float eta = x[(size_t)g*3], phi = x[(size_t)g*3 + 1];
    float d[NCL];
    float dmin = 1e30f;
#pragma unroll
    for (int k = 0; k < NCL; ++k) {
      float dx = eta - centers[2*k], dy = phi - centers[2*k+1];
      d[k] = dx*dx + dy*dy;
      dmin = fminf(dmin, d[k]);
    }
    float s = 0.f, ek[NCL];
#pragma unroll
    for (int k = 0; k < NCL; ++k) { ek[k] = expf(-T*(d[k]-dmin)); s += ek[k]; }
    float invs = 1.f/s;
#pragma unroll
    for (int k = 0; k < NCL; ++k) a_s[tid][k] = ek[k]*invs;
  }
  __syncthreads();
  if (tid < NCL) {   // deterministic column sums
    float s = 0.f;
    for (int n = 0; n < PJ; ++n) s += a_s[n][tid];
    colsum[tid] = s;
  }
  __syncthreads();
  int c = tid;
  float acc[NCL] = {};
  for (int n = 0; n < PJ; ++n) {
    float hv = h2f(h[(size_t)(j*PJ + n)*HD + c]);
#pragma unroll
    for (int k = 0; k < NCL; ++k) acc[k] += a_s[n][k]*hv;
  }
#pragma unroll
  for (int k = 0; k < NCL; ++k)
    out[(size_t)j*(NCL*HD) + k*HD + c] = acc[k] / (colsum[k] + 1e-8f);
}

// ---------------- host ----------------

template<typename OT>
static void run_plan(const float* x, const int* srcA, const int* tgtA,
                     const float* W1, const float* b1, const float* W2, const float* b2,
                     const float* W3, const float* b3, const float* W4, const float* b4,
                     const float* g1, const float* be1, const float* g2, const float* be2,
                     const float* g3, const float* be3, const float* centers, const float* log_temp,
                     float* out, char* wp0, hipStream_t stream) {
  char* wp = wp0;
  auto alloc = [&](size_t b) -> void* {
    void* p = (void*)wp;
    wp += (b + 255) & ~(size_t)255;
    return p;
  };
  u16*   X    = (u16*)alloc((size_t)NODES*HD*2);
  u16*   Y    = (u16*)alloc((size_t)NODES*HD*2);
  OT*    OUT  = (OT*)alloc((size_t)NODES*HD*sizeof(OT));
  float* dis  = (float*)alloc((size_t)NODES*4);
  int*   counts = (int*)alloc((size_t)NODES*4);
  int*   cursor = (int*)alloc((size_t)NODES*4);
  int*   rowptr = (int*)alloc((size_t)(NODES+1)*4);
  unsigned char* ccol = (unsigned char*)alloc((size_t)NEDGE);
  float* cw     = (float*)alloc((size_t)NEDGE*4);
  float* stats  = (float*)alloc((size_t)2*HD*4);
  // layer-1 fp32 scratch aliases into Y (free until layer 2); Wcat reuses Y too.
  float* Tall = (float*)Y;
  float* t3a  = Tall + (size_t)NODES*18;
  float* t3b  = t3a + (size_t)NODES*3;
  u16*   Wcat = Y;   // 256*1536 f16 = 786 KB, written after layer 1 is done with Tall

  // graph preprocessing
  hipMemsetAsync(counts, 0, (size_t)NODES*4, stream);
  k_dis<<<(NODES+255)/256, 256, 0, stream>>>(tgtA, dis);
  k_counts<<<(NEDGE+255)/256, 256, 0, stream>>>(tgtA, counts);
  k_scan<<<(NJETS+255)/256, 256, 0, stream>>>(counts, rowptr, cursor);
  k_fill<<<(NEDGE+255)/256, 256, 0, stream>>>(srcA, tgtA, dis, cursor, ccol, cw);

  const int NB = (NODES+255)/256;

  // ---- layer 1 (din=3) ----
  k_tall0<<<NB, 256, 0, stream>>>(x, Tall);
  k_prop3<<<NB, 256, 0, stream>>>(x,   x,   t3a, Tall+3,  1.f,  0.f, rowptr, ccol, cw);  // T1
  k_prop3<<<NB, 256, 0, stream>>>(t3a, x,   t3b, Tall+6,  2.f, -1.f, rowptr, ccol, cw);  // T2
  k_prop3<<<NB, 256, 0, stream>>>(t3b, t3a, t3a, Tall+9,  2.f, -1.f, rowptr, ccol, cw);  // T3
  k_prop3<<<NB, 256, 0, stream>>>(t3a, t3b, t3b, Tall+12, 2.f, -1.f, rowptr, ccol, cw);  // T4
  k_prop3<<<NB, 256, 0, stream>>>(t3b, t3a, t3a, Tall+15, 2.f, -1.f, rowptr, ccol, cw);  // T5
  k_gemm1<OT><<<NODES/64, 256, 0, stream>>>(Tall, W1, OUT);
  hipMemsetAsync(stats, 0, (size_t)2*HD*4, stream);
  k_bnstats<OT><<<1024, 256, 0, stream>>>(OUT, b1, stats);
  k_bnapply<OT><<<4096, 256, 0, stream>>>(OUT, b1, stats, g1, be1, X);

  // ---- layers 2..4: fused per-jet Cheb ----
  const float* Ws[3]  = {W2, W3, W4};
  const float* bs[3]  = {b2, b3, b4};
  const float* gs[2]  = {g2, g3};
  const float* bes[2] = {be2, be3};
  for (int L = 0; L < 3; ++L) {
    k_prepW<<<1536, 256, 0, stream>>>(Ws[L], Wcat);
    k_cheb<OT><<<NJETS, 512, 0, stream>>>(X, Wcat, OUT, rowptr, ccol, cw);
    if (L < 2) {
      hipMemsetAsync(stats, 0, (size_t)2*HD*4, stream);
      k_bnstats<OT><<<1024, 256, 0, stream>>>(OUT, bs[L], stats);
      k_bnapply<OT><<<4096, 256, 0, stream>>>(OUT, bs[L], stats, gs[L], bes[L], X);
    } else {
      k_rownorm<OT><<<NODES/4, 256, 0, stream>>>(OUT, bs[L], X);
    }
  }

  // ---- pooling ----
  k_pool<<<NJETS, 256, 0, stream>>>(X, x, centers, log_temp, out);
}

extern "C" void kernel_launch(void* const* d_in, const int* in_sizes, int n_in,
                              void* d_out, int out_size, void* d_ws, size_t ws_size,
                              hipStream_t stream) {
  (void)in_sizes; (void)n_in; (void)out_size;
  const float* x   = (const float*)d_in[0];
  const int*   ei  = (const int*)d_in[1];
  const int*   srcA = ei;
  const int*   tgtA = ei + NEDGE;
  const float* W1  = (const float*)d_in[3];
  const float* b1  = (const float*)d_in[4];
  const float* W2  = (const float*)d_in[5];
  const float* b2  = (const float*)d_in[6];
  const float* W3  = (const float*)d_in[7];
  const float* b3  = (const float*)d_in[8];
  const float* W4  = (const float*)d_in[9];
  const float* b4  = (const float*)d_in[10];
  const float* g1  = (const float*)d_in[11];
  const float* be1 = (const float*)d_in[12];
  const float* g2  = (const float*)d_in[13];
  const float* be2 = (const float*)d_in[14];
  const float* g3  = (const float*)d_in[15];
  const float* be3 = (const float*)d_in[16];
  const float* centers  = (const float*)d_in[17];
  const float* log_temp = (const float*)d_in[18];
  float* out = (float*)d_out;

  auto rb = [](size_t b) { return (b + 255) & ~(size_t)255; };
  auto plan_bytes = [&](size_t out_esz) {
    return 2*rb((size_t)NODES*HD*2) + rb((size_t)NODES*HD*out_esz)
         + 3*rb((size_t)NODES*4) + rb((size_t)(NODES+1)*4)
         + rb((size_t)NEDGE) + rb((size_t)NEDGE*4) + rb((size_t)2*HD*4);
  };
  size_t needA = plan_bytes(4);   // fp32 OUT  (~330 MB)
  size_t needB = plan_bytes(2);   // fp16 OUT  (~251 MB)
  fprintf(stderr, "[kernel_launch] ws_size=%zu needA=%zu needB=%zu\n", ws_size, needA, needB);

  if (d_ws == nullptr || ws_size < needB) {
    float code = 1.0e6f + (float)(ws_size >> 20);
    k_diag<<<1, 1, 0, stream>>>(out, code);
    return;
  }

  if (ws_size >= needA)
    run_plan<float>(x, srcA, tgtA, W1, b1, W2, b2, W3, b3, W4, b4,
                    g1, be1, g2, be2, g3, be3, centers, log_temp,
                    out, (char*)d_ws, stream);
  else
    run_plan<u16>(x, srcA, tgtA, W1, b1, W2, b2, W3, b3, W4, b4,
                  g1, be1, g2, be2, g3, be3, centers, log_temp,
                  out, (char*)d_ws, stream);
}

// Round 6
// 1983.987 us; speedup vs baseline: 7.6229x; 1.5545x over previous
//
#include <hip/hip_runtime.h>
#include <cstdio>

#define NODES 153600
#define PJ 150
#define NJETS 1024
#define DEG 16
#define NEDGE (NODES*DEG)
#define HD 256
#define NCL 10

#define LSTR 168   // padded stride (u16) for L2s rows and Ttr rows
#define TSTR 72    // padded stride (u16) for Tnat rows

typedef unsigned short u16;  // fp16 bit pattern
typedef _Float16 f16;
typedef f16 f16x8 __attribute__((ext_vector_type(8)));
typedef u16 u16x8 __attribute__((ext_vector_type(8)));
typedef u16 u16x4 __attribute__((ext_vector_type(4)));
typedef float f32x4 __attribute__((ext_vector_type(4)));

__device__ inline float h2f(u16 u) { union { u16 s; f16 h; } v; v.s = u; return (float)v.h; }
__device__ inline u16 f2h(float f) { union { u16 s; f16 h; } v; v.h = (f16)f; return v.s; }

template<typename T> __device__ inline float ldv(const T* p);
template<> __device__ inline float ldv<float>(const float* p) { return *p; }
template<> __device__ inline float ldv<u16>(const u16* p) { return h2f(*p); }
template<typename T> __device__ inline void stv(T* p, float v);
template<> __device__ inline void stv<float>(float* p, float v) { *p = v; }
template<> __device__ inline void stv<u16>(u16* p, float v) { *p = f2h(v); }

// ---------------- diagnostic ----------------
__global__ void k_diag(float* out, float code) {
  if (blockIdx.x == 0 && threadIdx.x == 0) out[0] = code;
}

// ---------------- graph preprocessing ----------------

__global__ __launch_bounds__(256) void k_dis(const int* __restrict__ tgt, float* __restrict__ dis) {
  int n = blockIdx.x*256 + threadIdx.x;
  if (n >= NODES) return;
  int cnt = 0;
#pragma unroll
  for (int j = 0; j < DEG; ++j) cnt += (tgt[n*DEG + j] != n) ? 1 : 0;
  dis[n] = (cnt > 0) ? rsqrtf((float)cnt) : 0.f;
}

__global__ __launch_bounds__(256) void k_counts(const int* __restrict__ tgt, int* __restrict__ counts) {
  int e = blockIdx.x*256 + threadIdx.x;
  if (e >= NEDGE) return;
  atomicAdd(&counts[tgt[e]], 1);
}

__global__ __launch_bounds__(256) void k_scan(const int* __restrict__ counts, int* __restrict__ rowptr, int* __restrict__ cursor) {
  int j = blockIdx.x*256 + threadIdx.x;
  if (j >= NJETS) return;
  int run = j*PJ*DEG;
  for (int l = 0; l < PJ; ++l) {
    int idx = j*PJ + l;
    int cnt = counts[idx];
    rowptr[idx] = run;
    cursor[idx] = run;
    run += cnt;
  }
  if (j == 0) rowptr[NODES] = NEDGE;
}

__global__ __launch_bounds__(256) void k_fill(const int* __restrict__ src_, const int* __restrict__ tgt_,
                                              const float* __restrict__ dis, int* __restrict__ cursor,
                                              unsigned char* __restrict__ ccol, float* __restrict__ cw) {
  int e = blockIdx.x*256 + threadIdx.x;
  if (e >= NEDGE) return;
  int s = src_[e], t = tgt_[e];
  int pos = atomicAdd(&cursor[t], 1);
  ccol[pos] = (unsigned char)(s % PJ);
  cw[pos] = (s != t) ? -(dis[s]*dis[t]) : 0.f;
}

// ---------------- dense per-jet 2*Laplacian: Lg[jet][160][160] f16 ----------------
// thread r exclusively owns row r: zero it, then accumulate its CSR edges (dups add).
__global__ __launch_bounds__(256) void k_prepL(const int* __restrict__ rowptr,
                                               const unsigned char* __restrict__ ccol,
                                               const float* __restrict__ cw,
                                               u16* __restrict__ Lg) {
  int j = blockIdx.x, tid = threadIdx.x;
  u16* L = Lg + (size_t)j*160*160;
  if (tid < 160) {
    u16x8 z = {0,0,0,0,0,0,0,0};
    for (int seg = 0; seg < 20; ++seg) *(u16x8*)&L[tid*160 + seg*8] = z;
    if (tid < PJ) {
      int es = rowptr[j*PJ + tid], ee = rowptr[j*PJ + tid + 1];
      u16* row = L + tid*160;
      for (int e = es; e < ee; ++e) {
        int c = (int)ccol[e];
        row[c] = f2h(h2f(row[c]) + 2.f*cw[e]);   // L2 = 2*Lhat
      }
    }
  }
}

// ---------------- layer 1 (din=3, fp32 scratch) ----------------

__global__ __launch_bounds__(256) void k_tall0(const float* __restrict__ x, float* __restrict__ tall) {
  int n = blockIdx.x*256 + threadIdx.x;
  if (n >= NODES) return;
  tall[n*18+0] = x[n*3+0]; tall[n*18+1] = x[n*3+1]; tall[n*18+2] = x[n*3+2];
}

__global__ __launch_bounds__(256) void k_prop3(const float* __restrict__ hin, const float* __restrict__ prev,
                                               float* __restrict__ out3, float* __restrict__ tallslot,
                                               float alpha, float beta,
                                               const int* __restrict__ rowptr, const unsigned char* __restrict__ ccol,
                                               const float* __restrict__ cw) {
  int t = blockIdx.x*256 + threadIdx.x;
  if (t >= NODES) return;
  int jb = (t/PJ)*PJ;
  int rs = rowptr[t], re = rowptr[t+1];
  float a0=0.f, a1=0.f, a2=0.f;
  for (int e = rs; e < re; ++e) {
    float w = cw[e];
    int s = (jb + (int)ccol[e])*3;
    a0 += w*hin[s]; a1 += w*hin[s+1]; a2 += w*hin[s+2];
  }
  float o0 = alpha*a0, o1 = alpha*a1, o2 = alpha*a2;
  if (beta != 0.f) { o0 += beta*prev[t*3]; o1 += beta*prev[t*3+1]; o2 += beta*prev[t*3+2]; }
  out3[t*3]=o0; out3[t*3+1]=o1; out3[t*3+2]=o2;
  tallslot[t*18]=o0; tallslot[t*18+1]=o1; tallslot[t*18+2]=o2;
}

template<typename OT>
__global__ __launch_bounds__(256) void k_gemm1(const float* __restrict__ tall, const float* __restrict__ W1,
                                               OT* __restrict__ outc) {
  __shared__ float wl[18*256];
  __shared__ float tl[64*18];
  int c = threadIdx.x;
  for (int i = c; i < 18*256; i += 256) wl[i] = W1[i];
  int n0 = blockIdx.x*64;
  __syncthreads();
  for (int i = c; i < 64*18; i += 256) tl[i] = tall[(size_t)n0*18 + i];
  __syncthreads();
  for (int n = 0; n < 64; ++n) {
    float acc = 0.f;
#pragma unroll
    for (int i = 0; i < 18; ++i) acc += tl[n*18 + i] * wl[i*256 + c];
    stv(&outc[(size_t)(n0+n)*HD + c], acc);
  }
}

// ---------------- W prep: WT[cout][k] f16, k = term*256 + cin ----------------
__global__ __launch_bounds__(256) void k_prepW(const float* __restrict__ W, u16* __restrict__ WT) {
  int i = blockIdx.x*256 + threadIdx.x;
  if (i >= 256*1536) return;
  int cout = i / 1536, k = i - cout*1536;
  int term = k >> 8, cin = k & 255;
  WT[i] = f2h(W[(size_t)term*65536 + cin*256 + cout]);
}

// ---------------- fused per-jet Chebyshev layer, all-MFMA ----------------
// Block = jet, 512 thr (8 waves = 2M x 4N). LDS: dense L2 [160][168] f16 (53.8K),
// Tnat ping-pong [2][160][72] (46.1K), Ttr single [64][168] (21.5K) = 121.3 KB.
// Per quarter q (64 input ch), per term t:
//   weight-MFMA: acc[5][4] += Tnat[cur] @ WT      (A natural layout, B global/L2$)
//   prop-MFMA  : pacc[5]    = L2s @ Ttr           (B^T = transposed layout)
//   barrier; epilogue: Tnext = pacc - Tprev (or 0.5*pacc at t=0), written to
//   Tnat[oth] (scalar) + Ttr (b64); barrier; swap.
template<typename OT>
__global__ __launch_bounds__(512, 1) void k_cheb(const u16* __restrict__ X,
                                                 const u16* __restrict__ WTu,
                                                 const u16* __restrict__ Lg,
                                                 OT* __restrict__ OUTp) {
  __shared__ u16 Ls[160*LSTR];
  __shared__ u16 Tn[2][160*TSTR];
  __shared__ u16 Tt[64*LSTR];
  int j = blockIdx.x, tid = threadIdx.x;
  int jb = j*PJ;
  int lane = tid & 63, wid = tid >> 6;
  int wm = wid >> 2, wn = wid & 3;
  int lr = lane & 15, lg = lane >> 4;
  const f16* WT = (const f16*)WTu;

  // stage dense L2 (once per block)
  {
    const u16* src = Lg + (size_t)j*25600;
    for (int i = tid; i < 3200; i += 512) {
      int row = i/20, seg = i - row*20;
      *(u16x8*)&Ls[row*LSTR + seg*8] = *(const u16x8*)&src[row*160 + seg*8];
    }
  }
  f32x4 acc[5][4];
#pragma unroll
  for (int a = 0; a < 5; ++a)
#pragma unroll
    for (int b = 0; b < 4; ++b) acc[a][b] = (f32x4)0.f;

  for (int q = 0; q < 4; ++q) {
    // stage T0 (natural) from X, zero pad rows 150..159
    __syncthreads();                     // L2 stage (q=0) / prior-term reads done
    for (int i = tid; i < 160*8; i += 512) {
      int row = i >> 3, seg = i & 7;
      u16x8 v = {0,0,0,0,0,0,0,0};
      if (row < PJ) v = *(const u16x8*)&X[(size_t)(jb+row)*HD + q*64 + seg*8];
      *(u16x8*)&Tn[0][row*TSTR + seg*8] = v;
    }
    __syncthreads();
    // build Ttr[c][r] from Tn[0]
    for (int i = tid; i < 1280; i += 512) {
      int c = i/20, r8 = (i - c*20)*8;
      u16x8 v;
#pragma unroll
      for (int u = 0; u < 8; ++u) v[u] = Tn[0][(r8+u)*TSTR + c];
      *(u16x8*)&Tt[c*LSTR + r8] = v;
    }
    __syncthreads();
    int cur = 0;
#pragma unroll 1
    for (int t = 0; t < 6; ++t) {
      // ---- weight GEMM: acc += T_t @ W_t ----
      int kbase = t*256 + q*64;
#pragma unroll
      for (int ks = 0; ks < 64; ks += 32) {
        f16x8 a[5], bv[4];
#pragma unroll
        for (int nf = 0; nf < 4; ++nf)
          bv[nf] = *(const f16x8*)&WT[(size_t)(wn*64 + nf*16 + lr)*1536 + kbase + ks + lg*8];
#pragma unroll
        for (int mf = 0; mf < 5; ++mf)
          a[mf] = *(const f16x8*)&Tn[cur][(wm*80 + mf*16 + lr)*TSTR + ks + lg*8];
#pragma unroll
        for (int nf = 0; nf < 4; ++nf)
#pragma unroll
          for (int mf = 0; mf < 5; ++mf)
            acc[mf][nf] = __builtin_amdgcn_mfma_f32_16x16x32_f16(a[mf], bv[nf], acc[mf][nf], 0, 0, 0);
      }
      // ---- prop MFMA: pacc = L2 @ T_t  (reads Ttr as B^T) ----
      f32x4 pacc[5];
      if (t < 5) {
#pragma unroll
        for (int mf = 0; mf < 5; ++mf) pacc[mf] = (f32x4)0.f;
#pragma unroll
        for (int ks = 0; ks < 5; ++ks) {
          f16x8 b = *(const f16x8*)&Tt[(wn*16 + lr)*LSTR + ks*32 + lg*8];
#pragma unroll
          for (int mf = 0; mf < 5; ++mf) {
            f16x8 a = *(const f16x8*)&Ls[(wm*80 + mf*16 + lr)*LSTR + ks*32 + lg*8];
            pacc[mf] = __builtin_amdgcn_mfma_f32_16x16x32_f16(a, b, pacc[mf], 0, 0, 0);
          }
        }
      }
      __syncthreads();   // all reads of Tt and Tn[cur] complete
      if (t < 5) {
        // epilogue: T_{t+1} = pacc - T_{t-1} (0.5*pacc at t=0); exclusive (r,c) ownership
        int oth = cur ^ 1;
        int c = wn*16 + lr;
#pragma unroll
        for (int mf = 0; mf < 5; ++mf) {
          int r0 = wm*80 + mf*16 + lg*4;
          u16x4 o;
#pragma unroll
          for (int e = 0; e < 4; ++e) {
            float v;
            if (t == 0) v = 0.5f*pacc[mf][e];
            else        v = pacc[mf][e] - h2f(Tn[oth][(r0+e)*TSTR + c]);
            o[e] = f2h(v);
            Tn[oth][(r0+e)*TSTR + c] = o[e];
          }
          *(u16x4*)&Tt[c*LSTR + r0] = o;
        }
      }
      __syncthreads();
      cur ^= 1;
    }
    // cur back to 0 (6 flips); next quarter restages Tn[0]/Tt
  }
  // ---- OUT epilogue (layout identical to r4/r5, HW-verified) ----
#pragma unroll
  for (int mf = 0; mf < 5; ++mf) {
    int row = wm*80 + mf*16 + lg*4;
#pragma unroll
    for (int e = 0; e < 4; ++e) {
      int r = row + e;
      if (r < PJ) {
#pragma unroll
        for (int nf = 0; nf < 4; ++nf) {
          int col = wn*64 + nf*16 + lr;
          stv(&OUTp[(size_t)(jb+r)*HD + col], acc[mf][nf][e]);
        }
      }
    }
  }
}

// ---------------- batchnorm (training stats, biased var) + leaky relu ----------------

template<typename OT>
__global__ __launch_bounds__(256) void k_bnstats(const OT* __restrict__ Cc, const float* __restrict__ bias,
                                                 float* __restrict__ stats) {
  int c = threadIdx.x;
  float bc = bias[c];
  float s = 0.f, s2 = 0.f;
  int rows_per = (NODES + gridDim.x - 1) / gridDim.x;
  int r0 = blockIdx.x * rows_per;
  int r1 = min(NODES, r0 + rows_per);
  for (int r = r0; r < r1; ++r) {
    float v = ldv(&Cc[(size_t)r*HD + c]) + bc;
    s += v; s2 += v*v;
  }
  atomicAdd(&stats[c], s);
  atomicAdd(&stats[HD + c], s2);
}

template<typename OT>
__global__ __launch_bounds__(256) void k_bnapply(const OT* __restrict__ Cc, const float* __restrict__ bias,
                                                 const float* __restrict__ stats, const float* __restrict__ g,
                                                 const float* __restrict__ be, u16* __restrict__ hout) {
  const float invN = 1.f/(float)NODES;
  int total = NODES*HD;
  for (int i = blockIdx.x*256 + threadIdx.x; i < total; i += gridDim.x*256) {
    int c = i & (HD-1);
    float m = stats[c]*invN;
    float v = stats[HD+c]*invN - m*m;
    float wq = rsqrtf(v + 1e-5f);
    float val = (ldv(&Cc[i]) + bias[c] - m)*wq*g[c] + be[c];
    hout[i] = f2h((val > 0.f) ? val : 0.01f*val);
  }
}

// ---------------- row L2 normalize (layer 4 output) ----------------

template<typename OT>
__global__ __launch_bounds__(256) void k_rownorm(const OT* __restrict__ Cc, const float* __restrict__ bias,
                                                 u16* __restrict__ hout) {
  int wave = threadIdx.x >> 6, lane = threadIdx.x & 63;
  int n = blockIdx.x*4 + wave;
  float v0 = ldv(&Cc[(size_t)n*HD + lane*4 + 0]) + bias[lane*4 + 0];
  float v1 = ldv(&Cc[(size_t)n*HD + lane*4 + 1]) + bias[lane*4 + 1];
  float v2 = ldv(&Cc[(size_t)n*HD + lane*4 + 2]) + bias[lane*4 + 2];
  float v3 = ldv(&Cc[(size_t)n*HD + lane*4 + 3]) + bias[lane*4 + 3];
  float ss = v0*v0 + v1*v1 + v2*v2 + v3*v3;
  for (int off = 32; off > 0; off >>= 1) ss += __shfl_down(ss, off, 64);
  ss = __shfl(ss, 0, 64);
  float inv = 1.f / fmaxf(sqrtf(ss), 1e-12f);
  hout[(size_t)n*HD + lane*4 + 0] = f2h(v0*inv);
  hout[(size_t)n*HD + lane*4 + 1] = f2h(v1*inv);
  hout[(size_t)n*HD + lane*4 + 2] = f2h(v2*inv);
  hout[(size_t)n*HD + lane*4 + 3] = f2h(v3*inv);
}

// ---------------- distance softmax pooling ----------------

__global__ __launch_bounds__(256) void k_pool(const u16* __restrict__ h, const float* __restrict__ x,
                                              const float* __restrict__ centers, const float* __restrict__ log_temp,
                                              float* __restrict__ out) {
  __shared__ float a_s[PJ][NCL];
  __shared__ float colsum[NCL];
  int j = blockIdx.x;
  int tid = threadIdx.x;
  float T = expf(fminf(fmaxf(log_temp[0], -2.f), 3.f));
  if (tid < PJ) {
    int g = j*PJ + tid;
    float eta = x[(size_t)g*3], phi = x[(size_t)g*3 + 1];
    float d[NCL];
    float dmin = 1e30f;
#pragma unroll
    for (int k = 0; k < NCL; ++k) {
      float dx = eta - centers[2*k], dy = phi - centers[2*k+1];
      d[k] = dx*dx + dy*dy;
      dmin = fminf(dmin, d[k]);
    }
    float s = 0.f, ek[NCL];
#pragma unroll
    for (int k = 0; k < NCL; ++k) { ek[k] = expf(-T*(d[k]-dmin)); s += ek[k]; }
    float invs = 1.f/s;
#pragma unroll
    for (int k = 0; k < NCL; ++k) a_s[tid][k] = ek[k]*invs;
  }
  __syncthreads();
  if (tid < NCL) {
    float s = 0.f;
    for (int n = 0; n < PJ; ++n) s += a_s[n][tid];
    colsum[tid] = s;
  }
  __syncthreads();
  int c = tid;
  float acc[NCL] = {};
  for (int n = 0; n < PJ; ++n) {
    float hv = h2f(h[(size_t)(j*PJ + n)*HD + c]);
#pragma unroll
    for (int k = 0; k < NCL; ++k) acc[k] += a_s[n][k]*hv;
  }
#pragma unroll
  for (int k = 0; k < NCL; ++k)
    out[(size_t)j*(NCL*HD) + k*HD + c] = acc[k] / (colsum[k] + 1e-8f);
}

// ---------------- host ----------------

template<typename OT>
static void run_plan(const float* x, const int* srcA, const int* tgtA,
                     const float* W1, const float* b1, const float* W2, const float* b2,
                     const float* W3, const float* b3, const float* W4, const float* b4,
                     const float* g1, const float* be1, const float* g2, const float* be2,
                     const float* g3, const float* be3, const float* centers, const float* log_temp,
                     float* out, char* wp0, hipStream_t stream) {
  char* wp = wp0;
  auto alloc = [&](size_t b) -> void* {
    void* p = (void*)wp;
    wp += (b + 255) & ~(size_t)255;
    return p;
  };
  u16*   X    = (u16*)alloc((size_t)NODES*HD*2);
  u16*   Y    = (u16*)alloc((size_t)NODES*HD*2);
  OT*    OUT  = (OT*)alloc((size_t)NODES*HD*sizeof(OT));
  float* dis  = (float*)alloc((size_t)NODES*4);
  int*   counts = (int*)alloc((size_t)NODES*4);
  int*   cursor = (int*)alloc((size_t)NODES*4);
  int*   rowptr = (int*)alloc((size_t)(NODES+1)*4);
  unsigned char* ccol = (unsigned char*)alloc((size_t)NEDGE);
  float* cw     = (float*)alloc((size_t)NEDGE*4);
  float* stats  = (float*)alloc((size_t)2*HD*4);
  // aliases into Y (Y never used as an activation buffer in layers 2-4):
  //   layer-1 fp32 scratch (first ~15 MB), THEN dense Lg (52.4 MB) + Wcat (786 KB)
  float* Tall = (float*)Y;
  float* t3a  = Tall + (size_t)NODES*18;
  float* t3b  = t3a + (size_t)NODES*3;
  u16*   Lg   = Y;
  u16*   Wcat = Y + (size_t)NJETS*160*160;

  // graph preprocessing
  hipMemsetAsync(counts, 0, (size_t)NODES*4, stream);
  k_dis<<<(NODES+255)/256, 256, 0, stream>>>(tgtA, dis);
  k_counts<<<(NEDGE+255)/256, 256, 0, stream>>>(tgtA, counts);
  k_scan<<<(NJETS+255)/256, 256, 0, stream>>>(counts, rowptr, cursor);
  k_fill<<<(NEDGE+255)/256, 256, 0, stream>>>(srcA, tgtA, dis, cursor, ccol, cw);

  const int NB = (NODES+255)/256;

  // ---- layer 1 (din=3) ----
  k_tall0<<<NB, 256, 0, stream>>>(x, Tall);
  k_prop3<<<NB, 256, 0, stream>>>(x,   x,   t3a, Tall+3,  1.f,  0.f, rowptr, ccol, cw);
  k_prop3<<<NB, 256, 0, stream>>>(t3a, x,   t3b, Tall+6,  2.f, -1.f, rowptr, ccol, cw);
  k_prop3<<<NB, 256, 0, stream>>>(t3b, t3a, t3a, Tall+9,  2.f, -1.f, rowptr, ccol, cw);
  k_prop3<<<NB, 256, 0, stream>>>(t3a, t3b, t3b, Tall+12, 2.f, -1.f, rowptr, ccol, cw);
  k_prop3<<<NB, 256, 0, stream>>>(t3b, t3a, t3a, Tall+15, 2.f, -1.f, rowptr, ccol, cw);
  k_gemm1<OT><<<NODES/64, 256, 0, stream>>>(Tall, W1, OUT);
  hipMemsetAsync(stats, 0, (size_t)2*HD*4, stream);
  k_bnstats<OT><<<1024, 256, 0, stream>>>(OUT, b1, stats);
  k_bnapply<OT><<<4096, 256, 0, stream>>>(OUT, b1, stats, g1, be1, X);

  // ---- dense Laplacian (after layer 1 frees the Y scratch) ----
  k_prepL<<<NJETS, 256, 0, stream>>>(rowptr, ccol, cw, Lg);

  // ---- layers 2..4: fused all-MFMA Cheb ----
  const float* Ws[3]  = {W2, W3, W4};
  const float* bs[3]  = {b2, b3, b4};
  const float* gs[2]  = {g2, g3};
  const float* bes[2] = {be2, be3};
  for (int L = 0; L < 3; ++L) {
    k_prepW<<<1536, 256, 0, stream>>>(Ws[L], Wcat);
    k_cheb<OT><<<NJETS, 512, 0, stream>>>(X, Wcat, Lg, OUT);
    if (L < 2) {
      hipMemsetAsync(stats, 0, (size_t)2*HD*4, stream);
      k_bnstats<OT><<<1024, 256, 0, stream>>>(OUT, bs[L], stats);
      k_bnapply<OT><<<4096, 256, 0, stream>>>(OUT, bs[L], stats, gs[L], bes[L], X);
    } else {
      k_rownorm<OT><<<NODES/4, 256, 0, stream>>>(OUT, bs[L], X);
    }
  }

  // ---- pooling ----
  k_pool<<<NJETS, 256, 0, stream>>>(X, x, centers, log_temp, out);
}

extern "C" void kernel_launch(void* const* d_in, const int* in_sizes, int n_in,
                              void* d_out, int out_size, void* d_ws, size_t ws_size,
                              hipStream_t stream) {
  (void)in_sizes; (void)n_in; (void)out_size;
  const float* x   = (const float*)d_in[0];
  const int*   ei  = (const int*)d_in[1];
  const int*   srcA = ei;
  const int*   tgtA = ei + NEDGE;
  const float* W1  = (const float*)d_in[3];
  const float* b1  = (const float*)d_in[4];
  const float* W2  = (const float*)d_in[5];
  const float* b2  = (const float*)d_in[6];
  const float* W3  = (const float*)d_in[7];
  const float* b3  = (const float*)d_in[8];
  const float* W4  = (const float*)d_in[9];
  const float* b4  = (const float*)d_in[10];
  const float* g1  = (const float*)d_in[11];
  const float* be1 = (const float*)d_in[12];
  const float* g2  = (const float*)d_in[13];
  const float* be2 = (const float*)d_in[14];
  const float* g3  = (const float*)d_in[15];
  const float* be3 = (const float*)d_in[16];
  const float* centers  = (const float*)d_in[17];
  const float* log_temp = (const float*)d_in[18];
  float* out = (float*)d_out;

  auto rb = [](size_t b) { return (b + 255) & ~(size_t)255; };
  auto plan_bytes = [&](size_t out_esz) {
    return 2*rb((size_t)NODES*HD*2) + rb((size_t)NODES*HD*out_esz)
         + 3*rb((size_t)NODES*4) + rb((size_t)(NODES+1)*4)
         + rb((size_t)NEDGE) + rb((size_t)NEDGE*4) + rb((size_t)2*HD*4);
  };
  size_t needA = plan_bytes(4);
  size_t needB = plan_bytes(2);
  fprintf(stderr, "[kernel_launch] ws_size=%zu needA=%zu needB=%zu\n", ws_size, needA, needB);

  if (d_ws == nullptr || ws_size < needB) {
    float code = 1.0e6f + (float)(ws_size >> 20);
    k_diag<<<1, 1, 0, stream>>>(out, code);
    return;
  }

  if (ws_size >= needA)
    run_plan<float>(x, srcA, tgtA, W1, b1, W2, b2, W3, b3, W4, b4,
                    g1, be1, g2, be2, g3, be3, centers, log_temp,
                    out, (char*)d_ws, stream);
  else
    run_plan<u16>(x, srcA, tgtA, W1, b1, W2, b2, W3, b3, W4, b4,
                  g1, be1, g2, be2, g3, be3, centers, log_temp,
                  out, (char*)d_ws, stream);
}